// Round 2
// baseline (7897.646 us; speedup 1.0000x reference)
//
#include <hip/hip_runtime.h>

#define B_ 2048
#define T_ 48
#define V_ 59
#define H_ 512
#define KP_ 640   // padded K for gates GEMM (59+59+512+10)
#define G4_ 2048  // 4*H
#define NB_ 256   // grid blocks (== CU count -> all co-resident)
#define NT_ 512   // threads per block (8 waves)
#define LDB_ 80   // LDS row stride in shorts (pad 64->80: 2-way bank alias only)

typedef __bf16 bf16x8 __attribute__((ext_vector_type(8)));
typedef float f32x4 __attribute__((ext_vector_type(4)));

__device__ __forceinline__ unsigned short f2bf(float x){
  union { float f; unsigned u; } v; v.f = x;
  unsigned r = (v.u + 0x7FFFu + ((v.u >> 16) & 1u)) >> 16;
  return (unsigned short)r;
}
__device__ __forceinline__ float sigf(float x){ return 1.f/(1.f+expf(-x)); }

// ---- workspace layout (bytes) ----
static const size_t OFF_Hws = 0;                               // h fp32 [2048*512]
static const size_t OFF_Cws = 4194304;                         // c fp32 [2048*512]
static const size_t OFF_LN  = 8388608;                         // loss_num[48]
static const size_t OFF_LD  = OFF_LN + 256;                    // loss_den[48]
static const size_t OFF_A   = OFF_LN + 512;                    // A bf16 [2048*640]
static const size_t OFF_WGT = OFF_A  + (size_t)B_*KP_*2;       // WgT bf16 [2048*640]
static const size_t OFF_WGH = OFF_WGT + (size_t)G4_*KP_*2;     // WghT f32 [59*512]
static const size_t OFF_WHI = OFF_WGH + 120832;                // WhistT f32 [512*59]
static const size_t OFF_WFR = OFF_WHI + 120832;                // WfrT f32 [59*59]
static const size_t OFF_WWC = OFF_WFR + 14080;                 // WwcT f32 [118*59]
static const size_t OFF_BAR = OFF_WWC + 28160;                 // barrier slots [128] u32

// device-scope grid barrier; each slot used exactly once per kernel call.
// Slots are zeroed by hipMemsetAsync before launch. All NB_ blocks are
// co-resident (grid == 256 == CU count, 1 small block/CU, launch_bounds caps
// VGPR), so spinning is deadlock-free.
__device__ __forceinline__ void gbar(unsigned* bar, int slot){
  __syncthreads();
  if (threadIdx.x == 0){
    __threadfence();   // release: make this block's writes device-visible
    __hip_atomic_fetch_add(&bar[slot], 1u, __ATOMIC_RELEASE, __HIP_MEMORY_SCOPE_AGENT);
    while (__hip_atomic_load(&bar[slot], __ATOMIC_ACQUIRE, __HIP_MEMORY_SCOPE_AGENT) < NB_)
      __builtin_amdgcn_s_sleep(1);
    __threadfence();   // acquire: invalidate stale cached lines
  }
  __syncthreads();
}

union SMem {
  struct {
    float d[8*64], m[8*64], x[8*64];
    float xh[8*64], xr[8*64], gx[8*64];
    float hs[8*H_];
    float red[16];
  } p1;
  struct {
    unsigned short A[128*LDB_];
    unsigned short Bt[128*LDB_];
  } p2;
};

__global__ __launch_bounds__(NT_, 2) void rits_fused(
    const float* __restrict__ x, const float* __restrict__ mk, const float* __restrict__ dl,
    const float* __restrict__ W_gh, const float* __restrict__ b_gh,
    const float* __restrict__ w_gx, const float* __restrict__ b_gx,
    const float* __restrict__ W_hist, const float* __restrict__ b_hist,
    const float* __restrict__ W_fr, const float* __restrict__ b_fr,
    const float* __restrict__ W_wc, const float* __restrict__ b_wc,
    const float* __restrict__ W_ih, const float* __restrict__ W_hh,
    const float* __restrict__ b_ih, const float* __restrict__ b_hh,
    char* __restrict__ ws,
    float* __restrict__ out_ximp, float* __restrict__ out_loss, float* __restrict__ out_hid)
{
  float*          h_ws   = (float*)(ws + OFF_Hws);
  float*          c_ws   = (float*)(ws + OFF_Cws);
  float*          lnum   = (float*)(ws + OFF_LN);
  float*          lden   = (float*)(ws + OFF_LD);
  unsigned short* A_buf  = (unsigned short*)(ws + OFF_A);
  unsigned short* WgT    = (unsigned short*)(ws + OFF_WGT);
  float*          WghT   = (float*)(ws + OFF_WGH);
  float*          WhistT = (float*)(ws + OFF_WHI);
  float*          WfrT   = (float*)(ws + OFF_WFR);
  float*          WwcT   = (float*)(ws + OFF_WWC);
  unsigned*       bar    = (unsigned*)(ws + OFF_BAR);

  __shared__ SMem sm;

  const int tid = threadIdx.x;
  const int bid = blockIdx.x;

  // XCD-aware tile swizzle: bid&7 ~ XCD; same-XCD blocks share a 256-row A panel.
  const int x8 = bid & 7;
  const int kb = bid >> 3;              // 0..31
  const int rt = x8*2 + (kb & 1);       // row tile 0..15 (128 rows each)
  const int ct = kb >> 1;               // col tile 0..15 (32 units each)
  const int r0 = rt * 128;              // phase2 batch-row base
  const int j0 = ct * 32;               // phase2 hidden-unit base
  const int r1 = rt*128 + ct*8;         // phase1 rows (8) — inside this XCD's panel

  // ---------------- init: transposes, packing, zeroing (every call) ----------------
  {
    int gt = bid*NT_ + tid;
    const int nt = NB_*NT_;
    for (int i = gt; i < V_*H_; i += nt){ int v = i >> 9, j = i & 511; WghT[i] = W_gh[j*V_ + v]; }
    for (int i = gt; i < H_*V_; i += nt){ int j = i / V_, v = i - j*V_; WhistT[i] = W_hist[v*H_ + j]; }
    for (int i = gt; i < V_*V_; i += nt){ int u = i / V_, v = i - u*V_; WfrT[i] = (u==v) ? 0.f : W_fr[v*V_ + u]; }
    for (int i = gt; i < 2*V_*V_; i += nt){ int u = i / V_, v = i - u*V_; WwcT[i] = W_wc[v*(2*V_) + u]; }
    for (int i = gt; i < G4_*KP_; i += nt){
      int n = i / KP_, k = i - n*KP_;
      float v = 0.f;
      if (k < 2*V_)      v = W_ih[n*(2*V_) + k];
      else if (k < 630)  v = W_hh[n*H_ + (k-118)];
      WgT[i] = f2bf(v);
    }
    for (int i = gt; i < 2*B_*H_; i += nt) ((float*)ws)[i] = 0.f;   // h, c
    for (int i = gt; i < 2*T_;    i += nt) lnum[i] = 0.f;           // lnum+lden (contiguous? no)
    if (gt < T_) { lnum[gt] = 0.f; lden[gt] = 0.f; }
    for (int i = gt; i < B_*10; i += nt){                           // A pad cols 630..640
      int b = i / 10, p = i - b*10;
      A_buf[(size_t)b*KP_ + 630 + p] = 0;
    }
  }
  gbar(bar, 0);

  for (int t = 0; t < T_; ++t) {
    // ================= phase 1: rows r1..r1+8 =================
    {
      if (tid < 8*V_) {
        int b = tid / V_, v = tid - b*V_;
        size_t g = ((size_t)(r1+b)*T_ + t)*V_ + v;
        sm.p1.d[b*64+v] = dl[g];
        sm.p1.m[b*64+v] = mk[g];
        sm.p1.x[b*64+v] = x[g];
      }
      __syncthreads();

      // gamma_h, decayed h~  (thread = hidden unit j)
      {
        int j = tid;
        float acc[8];
#pragma unroll
        for (int b=0;b<8;++b) acc[b]=0.f;
        for (int v=0; v<V_; ++v) {
          float wv = WghT[v*H_ + j];
#pragma unroll
          for (int b=0;b<8;++b) acc[b] += sm.p1.d[b*64+v]*wv;
        }
        float bg = b_gh[j];
#pragma unroll
        for (int b=0;b<8;++b) {
          float gh = expf(-fmaxf(acc[b]+bg, 0.f));
          float hv = h_ws[(size_t)(r1+b)*H_ + j] * gh;
          sm.p1.hs[b*H_+j] = hv;
          A_buf[(size_t)(r1+b)*KP_ + 118 + j] = f2bf(hv);
        }
      }
      __syncthreads();

      // x_h, x_r, gamma_x  (thread = (b, v))
      {
        int b = tid>>6, v = tid&63;
        if (v < V_) {
          const float4* hp4 = (const float4*)&sm.p1.hs[b*H_];
          float a0=0.f,a1=0.f,a2=0.f,a3=0.f;
          for (int j4=0;j4<H_/4;++j4){
            float4 h4 = hp4[j4];
            int j = j4*4;
            a0 += h4.x*WhistT[(j  )*V_+v];
            a1 += h4.y*WhistT[(j+1)*V_+v];
            a2 += h4.z*WhistT[(j+2)*V_+v];
            a3 += h4.w*WhistT[(j+3)*V_+v];
          }
          float xh = b_hist[v] + ((a0+a1)+(a2+a3));
          float mm = sm.p1.m[b*64+v], xx = sm.p1.x[b*64+v], dd = sm.p1.d[b*64+v];
          sm.p1.xh[b*64+v] = xh;
          sm.p1.xr[b*64+v] = mm*xx + (1.f-mm)*xh;
          sm.p1.gx[b*64+v] = expf(-fmaxf(dd*w_gx[v]+b_gx[v], 0.f));
          A_buf[(size_t)(r1+b)*KP_ + V_ + v] = f2bf(mm);
        }
      }
      __syncthreads();

      // xu, beta, x_comb, x_imp, loss partials
      float num = 0.f, den = 0.f;
      {
        int b = tid>>6, v = tid&63;
        if (v < V_) {
          float xu = b_fr[v], bt = b_wc[v];
          for (int u=0; u<V_; ++u) {
            xu += sm.p1.xr[b*64+u]*WfrT[u*V_+v];
            bt += sm.p1.gx[b*64+u]*WwcT[u*V_+v] + sm.p1.m[b*64+u]*WwcT[(V_+u)*V_+v];
          }
          float xh = sm.p1.xh[b*64+v];
          float xc = bt*xu + (1.f-bt)*xh;
          float mm = sm.p1.m[b*64+v], xx = sm.p1.x[b*64+v];
          num = fabsf(xx - xc)*mm;
          den = mm;
          float xi = mm*xx + (1.f-mm)*xc;
          out_ximp[((size_t)(r1+b)*T_ + t)*V_ + v] = xi;
          A_buf[(size_t)(r1+b)*KP_ + v] = f2bf(xi);
        }
      }
#pragma unroll
      for (int off=32; off; off>>=1){ num += __shfl_down(num, off); den += __shfl_down(den, off); }
      int wid = tid>>6, lane = tid&63;
      if (lane == 0){ sm.p1.red[wid] = num; sm.p1.red[8+wid] = den; }
      __syncthreads();
      if (tid == 0){
        float n=0.f, d=0.f;
        for (int i=0;i<8;++i){ n += sm.p1.red[i]; d += sm.p1.red[8+i]; }
        atomicAdd(&lnum[t], n);
        atomicAdd(&lden[t], d);
      }
    }
    gbar(bar, 1 + 2*t);

    // ================= phase 2: gate GEMM tile [r0..r0+128) x 128 gatecols =================
    {
      const int w    = tid >> 6;        // 8 waves
      const int rg   = w >> 1;          // 0..3: 32-row group
      const int uh   = w & 1;           // 0..1: 16-unit group
      const int lane = tid & 63;
      const int col  = lane & 15;
      const int quad = lane >> 4;

      f32x4 acc[2][4];
#pragma unroll
      for (int i=0;i<2;++i)
#pragma unroll
        for (int g=0;g<4;++g) acc[i][g] = (f32x4)(0.f);

      for (int s = 0; s < 10; ++s) {
#pragma unroll
        for (int p=0; p<2; ++p) {
          int idx = p*NT_ + tid;                  // 0..1023
          int row = idx >> 3, c8 = idx & 7;
          uint4 va = *reinterpret_cast<const uint4*>(A_buf + (size_t)(r0+row)*KP_ + s*64 + c8*8);
          *reinterpret_cast<uint4*>(&sm.p2.A[row*LDB_ + c8*8]) = va;
          int ng = ((row>>5)<<9) + j0 + (row&31); // gate*512 + unit
          uint4 vb = *reinterpret_cast<const uint4*>(WgT + (size_t)ng*KP_ + s*64 + c8*8);
          *reinterpret_cast<uint4*>(&sm.p2.Bt[row*LDB_ + c8*8]) = vb;
        }
        __syncthreads();
#pragma unroll
        for (int kk=0; kk<2; ++kk) {
          bf16x8 af[2], bfr[4];
#pragma unroll
          for (int mf=0; mf<2; ++mf)
            af[mf] = *reinterpret_cast<const bf16x8*>(&sm.p2.A[(rg*32 + mf*16 + col)*LDB_ + kk*32 + quad*8]);
#pragma unroll
          for (int g=0; g<4; ++g)
            bfr[g] = *reinterpret_cast<const bf16x8*>(&sm.p2.Bt[(g*32 + uh*16 + col)*LDB_ + kk*32 + quad*8]);
#pragma unroll
          for (int mf=0; mf<2; ++mf)
#pragma unroll
            for (int g=0; g<4; ++g)
              acc[mf][g] = __builtin_amdgcn_mfma_f32_16x16x32_bf16(af[mf], bfr[g], acc[mf][g], 0, 0, 0);
        }
        __syncthreads();
      }

      // LSTM epilogue: lane owns unit u, 4 gates in acc[mf][0..3]
      {
        int u = j0 + uh*16 + col;
        float bi  = b_ih[u]        + b_hh[u];
        float bf_ = b_ih[H_+u]     + b_hh[H_+u];
        float bg  = b_ih[2*H_+u]   + b_hh[2*H_+u];
        float bo  = b_ih[3*H_+u]   + b_hh[3*H_+u];
#pragma unroll
        for (int mf=0; mf<2; ++mf) {
#pragma unroll
          for (int r=0; r<4; ++r) {
            int b = r0 + rg*32 + mf*16 + quad*4 + r;
            float gi = acc[mf][0][r] + bi;
            float gf = acc[mf][1][r] + bf_;
            float gg = acc[mf][2][r] + bg;
            float go = acc[mf][3][r] + bo;
            size_t idx = (size_t)b*H_ + u;
            float co = c_ws[idx];
            float cn = sigf(gf)*co + sigf(gi)*tanhf(gg);
            float hn = sigf(go)*tanhf(cn);
            c_ws[idx] = cn;
            h_ws[idx] = hn;
            out_hid[((size_t)b*T_ + t)*H_ + u] = hn;
          }
        }
      }
    }
    gbar(bar, 2 + 2*t);
  }

  // ---------------- final loss ----------------
  if (bid == 0 && tid < 64) {
    float v = 0.f;
    if (tid < T_) v = lnum[tid]/(lden[tid] + 1e-5f);
#pragma unroll
    for (int off=32; off; off>>=1) v += __shfl_down(v, off);
    if (tid == 0) *out_loss = v;
  }
}

extern "C" void kernel_launch(void* const* d_in, const int* in_sizes, int n_in,
                              void* d_out, int out_size, void* d_ws, size_t ws_size,
                              hipStream_t stream)
{
  const float* x      = (const float*)d_in[0];
  const float* mk     = (const float*)d_in[1];
  const float* dl     = (const float*)d_in[2];
  const float* W_gh   = (const float*)d_in[3];
  const float* b_gh   = (const float*)d_in[4];
  const float* w_gx   = (const float*)d_in[5];
  const float* b_gx   = (const float*)d_in[6];
  const float* W_hist = (const float*)d_in[7];
  const float* b_hist = (const float*)d_in[8];
  const float* W_fr   = (const float*)d_in[9];
  const float* b_fr   = (const float*)d_in[10];
  const float* W_wc   = (const float*)d_in[11];
  const float* b_wc   = (const float*)d_in[12];
  const float* W_ih   = (const float*)d_in[13];
  const float* W_hh   = (const float*)d_in[14];
  const float* b_ih   = (const float*)d_in[15];
  const float* b_hh   = (const float*)d_in[16];

  char* ws = (char*)d_ws;
  float* out      = (float*)d_out;
  float* out_ximp = out;                                   // [B,T,V]
  float* out_loss = out + (size_t)B_*T_*V_;                // scalar
  float* out_hid  = out + (size_t)B_*T_*V_ + 1;            // [B,T,H]

  // zero the grid-barrier slots (ws is poisoned 0xAA before every launch)
  hipMemsetAsync(ws + OFF_BAR, 0, 128*sizeof(unsigned), stream);

  rits_fused<<<NB_, NT_, 0, stream>>>(x, mk, dl, W_gh, b_gh, w_gx, b_gx,
                                      W_hist, b_hist, W_fr, b_fr, W_wc, b_wc,
                                      W_ih, W_hh, b_ih, b_hh,
                                      ws, out_ximp, out_loss, out_hid);
}

// Round 3
// 2365.350 us; speedup vs baseline: 3.3389x; 3.3389x over previous
//
#include <hip/hip_runtime.h>

#define B_ 2048
#define T_ 48
#define V_ 59
#define H_ 512
#define KP_ 640   // padded K for gates GEMM (59+59+512+10)
#define G4_ 2048  // 4*H

typedef __bf16 bf16x8 __attribute__((ext_vector_type(8)));
typedef float f32x4 __attribute__((ext_vector_type(4)));

__device__ __forceinline__ unsigned short f2bf(float x){
  union { float f; unsigned u; } v; v.f = x;
  unsigned r = (v.u + 0x7FFFu + ((v.u >> 16) & 1u)) >> 16;
  return (unsigned short)r;
}
__device__ __forceinline__ float sigf(float x){ return 1.f/(1.f+expf(-x)); }

// ---- workspace layout (bytes) ----
static const size_t OFF_Hws = 0;                               // h fp32 [2048*512]
static const size_t OFF_Cws = 4194304;                         // c fp32 [2048*512]
static const size_t OFF_LN  = 8388608;                         // loss_num[48]
static const size_t OFF_LD  = OFF_LN + 256;                    // loss_den[48]
static const size_t MEMSET_BYTES = OFF_LN + 512;               // zero h, c, loss
static const size_t OFF_A   = OFF_LN + 512;                    // A bf16 [2048*640] (16B aligned)
static const size_t OFF_WGT = OFF_A  + (size_t)B_*KP_*2;       // WgT bf16 [2048*640]
static const size_t OFF_WGH = OFF_WGT + (size_t)G4_*KP_*2;     // WghT f32 [59*512]
static const size_t OFF_WHB = OFF_WGH + 120832;                // WhB bf16 [64*512]
static const size_t OFF_WFR = OFF_WHB + 120832;                // WfrT f32 [59*59]
static const size_t OFF_WWC = OFF_WFR + 14080;                 // WwcT f32 [118*59]

// ------------------- init: transposes / packing -------------------
__global__ void init_k(const float* __restrict__ W_gh, const float* __restrict__ W_hist,
                       const float* __restrict__ W_fr, const float* __restrict__ W_wc,
                       const float* __restrict__ W_ih, const float* __restrict__ W_hh,
                       float* __restrict__ WghT, unsigned short* __restrict__ WhB,
                       float* __restrict__ WfrT, float* __restrict__ WwcT,
                       unsigned short* __restrict__ WgT, unsigned short* __restrict__ A_buf)
{
  int tid = blockIdx.x*blockDim.x + threadIdx.x;
  int nt  = gridDim.x*blockDim.x;
  // WghT[v*512+j] = W_gh[j*59+v]
  for (int i = tid; i < V_*H_; i += nt){ int v = i >> 9, j = i & 511; WghT[i] = W_gh[j*V_ + v]; }
  // WhB[n*512+k] = bf16(W_hist[n*512+k]) for n<59, else 0  (B-operand rows for x_h MFMA)
  for (int i = tid; i < 64*H_; i += nt){ int n = i >> 9; WhB[i] = (n < V_) ? f2bf(W_hist[i]) : (unsigned short)0; }
  // WfrT[u*59+v] = (u==v) ? 0 : W_fr[v*59+u]
  for (int i = tid; i < V_*V_; i += nt){ int u = i / V_, v = i - u*V_; WfrT[i] = (u==v) ? 0.f : W_fr[v*V_ + u]; }
  // WwcT[u*59+v] = W_wc[v*118+u]
  for (int i = tid; i < 2*V_*V_; i += nt){ int u = i / V_, v = i - u*V_; WwcT[i] = W_wc[v*(2*V_) + u]; }
  // WgT[n*640+k]: k<118 -> W_ih[n][k]; k<630 -> W_hh[n][k-118]; else 0
  for (int i = tid; i < G4_*KP_; i += nt){
    int n = i / KP_, k = i - n*KP_;
    float v = 0.f;
    if (k < 2*V_)      v = W_ih[n*(2*V_) + k];
    else if (k < 630)  v = W_hh[n*H_ + (k-118)];
    WgT[i] = f2bf(v);
  }
  // zero A pad cols 630..639 once (phase1 never touches them)
  for (int i = tid; i < B_*10; i += nt){ int b = i / 10, p = i - b*10; A_buf[(size_t)b*KP_ + 630 + p] = 0; }
}

// ------------------- phase 1: decay, history (MFMA), regression, combine -------------------
__global__ __launch_bounds__(512) void phase1(int t,
    const float* __restrict__ x, const float* __restrict__ mk, const float* __restrict__ dl,
    const float* __restrict__ b_gh, const float* __restrict__ w_gx, const float* __restrict__ b_gx,
    const float* __restrict__ b_hist, const float* __restrict__ b_fr, const float* __restrict__ b_wc,
    const float* __restrict__ WghT, const unsigned short* __restrict__ WhB,
    const float* __restrict__ WfrT, const float* __restrict__ WwcT,
    const float* __restrict__ h_ws, unsigned short* __restrict__ A_buf,
    float* __restrict__ out_ximp, float* __restrict__ loss_num, float* __restrict__ loss_den)
{
  __shared__ float d_s[8*64], m_s[8*64], x_s[8*64];
  __shared__ float xh_s[8*64], xr_s[8*64], gx_s[8*64];
  __shared__ unsigned short hA[16*520];   // A-operand for x_h MFMA; rows 0..7 real, stride 520 (bank-clean)
  __shared__ float red[16];
  const int tid = threadIdx.x;
  const int r1  = blockIdx.x * 8;

  if (tid < 8*V_) {
    int b = tid / V_, v = tid - b*V_;
    size_t g = ((size_t)(r1+b)*T_ + t)*V_ + v;
    d_s[b*64+v] = dl[g];
    m_s[b*64+v] = mk[g];
    x_s[b*64+v] = x[g];
  }
  __syncthreads();

  // gamma_h and decayed h~ ; thread = hidden unit j
  {
    int j = tid;
    float acc[8];
#pragma unroll
    for (int b=0;b<8;++b) acc[b]=0.f;
    for (int v=0; v<V_; ++v) {
      float wv = WghT[v*H_ + j];
#pragma unroll
      for (int b=0;b<8;++b) acc[b] += d_s[b*64+v]*wv;
    }
    float bg = b_gh[j];
#pragma unroll
    for (int b=0;b<8;++b) {
      float gh = expf(-fmaxf(acc[b]+bg, 0.f));
      float hv = h_ws[(size_t)(r1+b)*H_ + j] * gh;
      unsigned short hb = f2bf(hv);
      hA[b*520 + j] = hb;                               // rows 8..15 left garbage: only D rows 0..7 used
      A_buf[(size_t)(r1+b)*KP_ + 118 + j] = hb;
    }
  }
  __syncthreads();

  if (tid < 256) {
    // waves 0..3: x_h = h~ @ W_hist^T via one 16x16x32 MFMA chain per wave (wave w owns v-tile w)
    const int w = tid >> 6, lane = tid & 63, col = lane & 15, quad = lane >> 4;
    f32x4 acc = (f32x4)(0.f);
    const unsigned short* wb = WhB + (size_t)(w*16 + col)*H_;
#pragma unroll
    for (int kk = 0; kk < 16; ++kk) {
      bf16x8 a  = *reinterpret_cast<const bf16x8*>(&hA[col*520 + kk*32 + quad*8]);
      bf16x8 bb = *reinterpret_cast<const bf16x8*>(wb + kk*32 + quad*8);
      acc = __builtin_amdgcn_mfma_f32_16x16x32_bf16(a, bb, acc, 0, 0, 0);
    }
    if (quad < 2) {                       // D rows 0..7 are the real batch rows
      int v = w*16 + col;
      float bh = (v < V_) ? b_hist[v] : 0.f;
#pragma unroll
      for (int r=0; r<4; ++r) xh_s[(quad*4+r)*64 + v] = acc[r] + bh;
    }
  } else {
    // waves 4..7: gamma_x + mask column of A
    for (int i = tid - 256; i < 512; i += 256) {
      int b = i >> 6, v = i & 63;
      if (v < V_) {
        float mm = m_s[b*64+v], dd = d_s[b*64+v];
        gx_s[b*64+v] = expf(-fmaxf(dd*w_gx[v]+b_gx[v], 0.f));
        A_buf[(size_t)(r1+b)*KP_ + V_ + v] = f2bf(mm);
      }
    }
  }
  __syncthreads();

  // x_r
  {
    int b = tid>>6, v = tid&63;
    if (v < V_) {
      float mm = m_s[b*64+v];
      xr_s[b*64+v] = mm*x_s[b*64+v] + (1.f-mm)*xh_s[b*64+v];
    }
  }
  __syncthreads();

  // xu (feature regression), beta, x_comb, x_imp, loss partials
  float num = 0.f, den = 0.f;
  {
    int b = tid>>6, v = tid&63;
    if (v < V_) {
      float xu = b_fr[v], bt = b_wc[v];
      for (int u=0; u<V_; ++u) {
        xu += xr_s[b*64+u]*WfrT[u*V_+v];
        bt += gx_s[b*64+u]*WwcT[u*V_+v] + m_s[b*64+u]*WwcT[(V_+u)*V_+v];
      }
      float xh = xh_s[b*64+v];
      float xc = bt*xu + (1.f-bt)*xh;
      float mm = m_s[b*64+v], xx = x_s[b*64+v];
      num = fabsf(xx - xc)*mm;
      den = mm;
      float xi = mm*xx + (1.f-mm)*xc;
      out_ximp[((size_t)(r1+b)*T_ + t)*V_ + v] = xi;
      A_buf[(size_t)(r1+b)*KP_ + v] = f2bf(xi);
    }
  }
#pragma unroll
  for (int off=32; off; off>>=1){ num += __shfl_down(num, off); den += __shfl_down(den, off); }
  int wid = tid>>6, lane = tid&63;
  if (lane == 0){ red[wid] = num; red[8+wid] = den; }
  __syncthreads();
  if (tid == 0){
    float n=0.f, d=0.f;
    for (int i=0;i<8;++i){ n += red[i]; d += red[8+i]; }
    atomicAdd(&loss_num[t], n);
    atomicAdd(&loss_den[t], d);
  }
}

// ------------------- phase 2: gate GEMM (bf16 MFMA, xor-swizzled LDS) + LSTM -------------------
__global__ __launch_bounds__(512) void phase2(int t,
    const unsigned short* __restrict__ A_buf, const unsigned short* __restrict__ WgT,
    const float* __restrict__ b_ih, const float* __restrict__ b_hh,
    float* __restrict__ h_ws, float* __restrict__ c_ws, float* __restrict__ out_hid)
{
  // LDS as 16B chunks: row r (0..127) has 8 chunks; chunk c stored at c ^ (r&7).
  // Frag read (16-lane phase, fixed quad): banks (4*((kk*4+quad)^(r&7))) cover all 32, 2-way -> free.
  __shared__ uint4 ldsA[128*8];
  __shared__ uint4 ldsB[128*8];
  const int tid  = threadIdx.x;
  const int r0   = blockIdx.x * 128;   // batch rows
  const int j0   = blockIdx.y * 32;    // hidden units
  const int w    = tid >> 6;           // 8 waves
  const int rg   = w >> 1;             // 32-row group
  const int uh   = w & 1;              // 16-unit group
  const int lane = tid & 63;
  const int col  = lane & 15;
  const int quad = lane >> 4;

  f32x4 acc[2][4];
#pragma unroll
  for (int i=0;i<2;++i)
#pragma unroll
    for (int g=0;g<4;++g) acc[i][g] = (f32x4)(0.f);

  for (int s = 0; s < 10; ++s) {       // K = 640 in 10 stages of 64
#pragma unroll
    for (int p=0; p<2; ++p) {
      int idx = p*512 + tid;           // 0..1023 chunk id
      int r = idx >> 3, c = idx & 7;
      ldsA[r*8 + (c ^ (r&7))] = *reinterpret_cast<const uint4*>(A_buf + (size_t)(r0+r)*KP_ + s*64 + c*8);
      int ng = ((r>>5)<<9) + j0 + (r&31);           // gate*512 + unit
      ldsB[r*8 + (c ^ (r&7))] = *reinterpret_cast<const uint4*>(WgT + (size_t)ng*KP_ + s*64 + c*8);
    }
    __syncthreads();
#pragma unroll
    for (int kk=0; kk<2; ++kk) {
      bf16x8 af[2], bfr[4];
#pragma unroll
      for (int mf=0; mf<2; ++mf) {
        int r = rg*32 + mf*16 + col;
        af[mf] = *reinterpret_cast<const bf16x8*>(&ldsA[r*8 + ((kk*4+quad) ^ (r&7))]);
      }
#pragma unroll
      for (int g=0; g<4; ++g) {
        int r = g*32 + uh*16 + col;
        bfr[g] = *reinterpret_cast<const bf16x8*>(&ldsB[r*8 + ((kk*4+quad) ^ (r&7))]);
      }
#pragma unroll
      for (int mf=0; mf<2; ++mf)
#pragma unroll
        for (int g=0; g<4; ++g)
          acc[mf][g] = __builtin_amdgcn_mfma_f32_16x16x32_bf16(af[mf], bfr[g], acc[mf][g], 0, 0, 0);
    }
    __syncthreads();
  }

  // LSTM epilogue: lane owns unit u, 4 gates in acc[mf][0..3]
  {
    int u = j0 + uh*16 + col;
    float bi  = b_ih[u]        + b_hh[u];
    float bf_ = b_ih[H_+u]     + b_hh[H_+u];
    float bg  = b_ih[2*H_+u]   + b_hh[2*H_+u];
    float bo  = b_ih[3*H_+u]   + b_hh[3*H_+u];
#pragma unroll
    for (int mf=0; mf<2; ++mf) {
#pragma unroll
      for (int r=0; r<4; ++r) {
        int b = r0 + rg*32 + mf*16 + quad*4 + r;
        float gi = acc[mf][0][r] + bi;
        float gf = acc[mf][1][r] + bf_;
        float gg = acc[mf][2][r] + bg;
        float go = acc[mf][3][r] + bo;
        size_t idx = (size_t)b*H_ + u;
        float co = c_ws[idx];
        float cn = sigf(gf)*co + sigf(gi)*tanhf(gg);
        float hn = sigf(go)*tanhf(cn);
        c_ws[idx] = cn;
        h_ws[idx] = hn;
        out_hid[((size_t)b*T_ + t)*H_ + u] = hn;
      }
    }
  }
}

// ------------------- final loss reduction -------------------
__global__ void loss_k(const float* __restrict__ loss_num, const float* __restrict__ loss_den,
                       float* __restrict__ out_loss)
{
  int tid = threadIdx.x;
  float v = 0.f;
  if (tid < T_) v = loss_num[tid]/(loss_den[tid] + 1e-5f);
#pragma unroll
  for (int off=32; off; off>>=1) v += __shfl_down(v, off);
  if (tid == 0) *out_loss = v;
}

extern "C" void kernel_launch(void* const* d_in, const int* in_sizes, int n_in,
                              void* d_out, int out_size, void* d_ws, size_t ws_size,
                              hipStream_t stream)
{
  const float* x      = (const float*)d_in[0];
  const float* mk     = (const float*)d_in[1];
  const float* dl     = (const float*)d_in[2];
  const float* W_gh   = (const float*)d_in[3];
  const float* b_gh   = (const float*)d_in[4];
  const float* w_gx   = (const float*)d_in[5];
  const float* b_gx   = (const float*)d_in[6];
  const float* W_hist = (const float*)d_in[7];
  const float* b_hist = (const float*)d_in[8];
  const float* W_fr   = (const float*)d_in[9];
  const float* b_fr   = (const float*)d_in[10];
  const float* W_wc   = (const float*)d_in[11];
  const float* b_wc   = (const float*)d_in[12];
  const float* W_ih   = (const float*)d_in[13];
  const float* W_hh   = (const float*)d_in[14];
  const float* b_ih   = (const float*)d_in[15];
  const float* b_hh   = (const float*)d_in[16];

  char* ws = (char*)d_ws;
  float*          h_ws   = (float*)(ws + OFF_Hws);
  float*          c_ws   = (float*)(ws + OFF_Cws);
  float*          lnum   = (float*)(ws + OFF_LN);
  float*          lden   = (float*)(ws + OFF_LD);
  unsigned short* A_buf  = (unsigned short*)(ws + OFF_A);
  unsigned short* WgT    = (unsigned short*)(ws + OFF_WGT);
  float*          WghT   = (float*)(ws + OFF_WGH);
  unsigned short* WhB    = (unsigned short*)(ws + OFF_WHB);
  float*          WfrT   = (float*)(ws + OFF_WFR);
  float*          WwcT   = (float*)(ws + OFF_WWC);

  float* out      = (float*)d_out;
  float* out_ximp = out;                                   // [B,T,V]
  float* out_loss = out + (size_t)B_*T_*V_;                // scalar
  float* out_hid  = out + (size_t)B_*T_*V_ + 1;            // [B,T,H]

  hipMemsetAsync(d_ws, 0, MEMSET_BYTES, stream);           // h, c, loss accumulators
  init_k<<<1024, 256, 0, stream>>>(W_gh, W_hist, W_fr, W_wc, W_ih, W_hh,
                                   WghT, WhB, WfrT, WwcT, WgT, A_buf);
  for (int t = 0; t < T_; ++t) {
    phase1<<<256, 512, 0, stream>>>(t, x, mk, dl, b_gh, w_gx, b_gx, b_hist, b_fr, b_wc,
                                    WghT, WhB, WfrT, WwcT, h_ws, A_buf,
                                    out_ximp, lnum, lden);
    phase2<<<dim3(16,16), 512, 0, stream>>>(t, A_buf, WgT, b_ih, b_hh,
                                            h_ws, c_ws, out_hid);
  }
  loss_k<<<1, 64, 0, stream>>>(lnum, lden, out_loss);
}